// Round 5
// baseline (795.277 us; speedup 1.0000x reference)
//
#include <hip/hip_runtime.h>
#include <stdint.h>

#define B_  256
#define T_  512
#define H_  128
#define NSW 6

typedef __bf16 bf2_t __attribute__((ext_vector_type(2)));

// float -> bf16 round-to-nearest-even
__device__ __forceinline__ unsigned short f2bf(float f){
  unsigned u = __float_as_uint(f);
  unsigned r = u + 0x7FFFu + ((u >> 16) & 1u);
  return (unsigned short)(r >> 16);
}

// acc += dot2(bf16x2 w, bf16x2 h)
__device__ __forceinline__ float dot2bf(unsigned wpair, unsigned hpair, float acc){
#if __has_builtin(__builtin_amdgcn_fdot2_f32_bf16)
  return __builtin_amdgcn_fdot2_f32_bf16(__builtin_bit_cast(bf2_t, wpair),
                                         __builtin_bit_cast(bf2_t, hpair), acc, false);
#else
  asm("v_dot2_f32_bf16 %0, %1, %2, %0" : "+v"(acc) : "v"(wpair), "v"(hpair));
  return acc;
#endif
}

// LDS-only barrier: drains lgkmcnt but NOT vmcnt -> weight prefetch stays in flight.
__device__ __forceinline__ void lds_barrier(){
  asm volatile("s_waitcnt lgkmcnt(0)\ns_barrier" ::: "memory");
}

// Scalar-component bind: forces the load producing this value to be issued and
// complete by this point. Direct register operand -> legal for LLVM.
__device__ __forceinline__ void bind1(unsigned v){
  asm volatile("" :: "v"(v));
}

// Pack weights: dst[(g*6+s)*2048 + j8*128 + i] = uint4 of bf16 W_g[s][i][8*j8+0..7]
__global__ __launch_bounds__(256) void pack_weights(const float* __restrict__ Wr,
                                                    const float* __restrict__ Wz,
                                                    const float* __restrict__ Wn,
                                                    uint4* __restrict__ dst){
  int idx = blockIdx.x * 256 + threadIdx.x;
  if (idx >= 3 * NSW * 2048) return;
  int g  = idx / (NSW * 2048);
  int r0 = idx % (NSW * 2048);
  int s  = r0 / 2048;
  int q  = r0 % 2048;
  int j8 = q / 128;
  int i  = q % 128;
  const float* W = (g == 0) ? Wr : (g == 1) ? Wz : Wn;
  const float* src = W + (size_t)s * (H_*H_) + (size_t)i * H_ + 8 * j8;
  uint4 o;
  o.x = (unsigned)f2bf(src[0]) | ((unsigned)f2bf(src[1]) << 16);
  o.y = (unsigned)f2bf(src[2]) | ((unsigned)f2bf(src[3]) << 16);
  o.z = (unsigned)f2bf(src[4]) | ((unsigned)f2bf(src[5]) << 16);
  o.w = (unsigned)f2bf(src[6]) | ((unsigned)f2bf(src[7]) << 16);
  dst[idx] = o;
}

__global__ __launch_bounds__(384, 1) void gru_run(const float* __restrict__ stim,
    const int*   __restrict__ swid,  const float* __restrict__ mask,
    const float* __restrict__ Win,   const float* __restrict__ binp,
    const float* __restrict__ b_hr,  const float* __restrict__ b_hz, const float* __restrict__ b_hn,
    const float* __restrict__ Wo,    const float* __restrict__ bo,
    const uint4* __restrict__ Wpk,   float* __restrict__ out)
{
  const int b    = blockIdx.x;
  const int tid  = threadIdx.x;
  const int g    = tid >> 7;
  const int i    = tid & 127;
  const int lane = tid & 63;

  __shared__ float    s_stim[T_ * 8];     // 16 KB
  __shared__ float    s_mask[T_];         //  2 KB
  __shared__ int      s_sid[T_];          //  2 KB
  __shared__ float    s_b[3 * NSW * H_];  //  9 KB
  __shared__ float    s_r[H_];
  __shared__ float    s_z[H_];
  __shared__ float    s_h[2][H_];         // fp32 h state
  __shared__ unsigned s_hb[2][64];        // h packed as bf16 pairs

  // ---- preload chain-local data ----
  for (int k = tid; k < T_ * 8; k += 384) s_stim[k] = stim[(size_t)b * T_ * 8 + k];
  for (int k = tid; k < T_; k += 384){
    s_mask[k] = mask[(size_t)b * T_ + k];
    int ss = swid[(size_t)b * T_ + k];
    s_sid[k] = ss < 0 ? 0 : (ss > NSW - 1 ? NSW - 1 : ss);
  }
  for (int k = tid; k < NSW * H_; k += 384){
    s_b[k]                = b_hr[k];
    s_b[NSW * H_ + k]     = b_hz[k];
    s_b[2 * NSW * H_ + k] = b_hn[k];
  }
  if (tid < H_) s_h[0][tid] = 0.f;
  if (tid < 64) s_hb[0][tid] = 0u;

  float winr[8];
  #pragma unroll
  for (int s2 = 0; s2 < 8; ++s2) winr[s2] = Win[tid * 8 + s2];
  const float binr = binp[tid];

  float wo_a = 0.f, wo_b = 0.f, bo_r = 0.f;
  const int kk = (tid >= 192 && tid < 256) ? 1 : 0;
  if (g == 1){
    wo_a = Wo[kk * H_ + lane];
    wo_b = Wo[kk * H_ + 64 + lane];
    bo_r = bo[kk];
  }

  const uint4* gbase = Wpk + (size_t)g * (NSW * 2048) + i;
  float* outp = out + (size_t)b * T_ * 2;

  __syncthreads();

  // preload step-0 weights
  uint4 WA[16], WB[16];
  {
    int ss0 = __builtin_amdgcn_readfirstlane(s_sid[0]);
    const uint4* wp = gbase + (size_t)ss0 * 2048;
    #pragma unroll
    for (int j = 0; j < 16; ++j) WA[j] = wp[j * 128];
  }

#define STEP(t, WC, WN) do {                                                   \
    const int cur = (t) & 1, nxt = cur ^ 1;                                    \
    int tn  = ((t) + 1 < T_) ? (t) + 1 : (t);                                  \
    int ssn = __builtin_amdgcn_readfirstlane(s_sid[tn]);                       \
    { const uint4* wp = gbase + (size_t)ssn * 2048;                            \
      _Pragma("unroll")                                                        \
      for (int j = 0; j < 16; ++j) WN[j] = wp[j * 128]; }                      \
    int ssc = __builtin_amdgcn_readfirstlane(s_sid[(t)]);                      \
    unsigned hp = s_hb[cur][lane];                                             \
    float4 sa = *reinterpret_cast<const float4*>(&s_stim[(t) * 8]);            \
    float4 sb = *reinterpret_cast<const float4*>(&s_stim[(t) * 8 + 4]);        \
    float x = binr + winr[0]*sa.x + winr[1]*sa.y + winr[2]*sa.z + winr[3]*sa.w \
                   + winr[4]*sb.x + winr[5]*sb.y + winr[6]*sb.z + winr[7]*sb.w;\
    float a0 = 0.f, a1 = 0.f, a2 = 0.f, a3 = 0.f;                              \
    _Pragma("unroll")                                                          \
    for (int j8 = 0; j8 < 16; ++j8){                                           \
      uint4 w = WC[j8];                                                        \
      unsigned h0 = (unsigned)__builtin_amdgcn_readlane((int)hp, 4*j8 + 0);    \
      unsigned h1 = (unsigned)__builtin_amdgcn_readlane((int)hp, 4*j8 + 1);    \
      unsigned h2 = (unsigned)__builtin_amdgcn_readlane((int)hp, 4*j8 + 2);    \
      unsigned h3 = (unsigned)__builtin_amdgcn_readlane((int)hp, 4*j8 + 3);    \
      a0 = dot2bf(w.x, h0, a0);                                                \
      a1 = dot2bf(w.y, h1, a1);                                                \
      a2 = dot2bf(w.z, h2, a2);                                                \
      a3 = dot2bf(w.w, h3, a3);                                                \
    }                                                                          \
    float acc = ((a0 + a1) + (a2 + a3)) + s_b[g * (NSW*H_) + ssc * H_ + i];    \
    if (g == 0)      s_r[i] = 1.f / (1.f + __expf(-(x + acc)));                \
    else if (g == 1) s_z[i] = 1.f / (1.f + __expf(-(x + acc)));                \
    lds_barrier();                                                             \
    if (g == 2){                                                               \
      float r = s_r[i], z = s_z[i], hprev = s_h[cur][i];                       \
      float e = __expf(2.f * (x + r * acc));                                   \
      float n = 1.f - 2.f / (e + 1.f);                                         \
      float hnew = (1.f - z) * n + z * hprev;                                  \
      float mt = s_mask[(t)];                                                  \
      float ho = mt * hnew + (1.f - mt) * hprev;                               \
      s_h[nxt][i] = ho;                                                        \
      ((unsigned short*)s_hb[nxt])[i] = f2bf(ho);                              \
    }                                                                          \
    /* pin the pipeline: next-step loads issued & complete by end of step t */ \
    _Pragma("unroll")                                                          \
    for (int j = 0; j < 16; ++j){ bind1(WN[j].x); bind1(WN[j].y);              \
                                  bind1(WN[j].z); bind1(WN[j].w); }            \
    lds_barrier();                                                             \
    if (g == 1){                                                               \
      float p = wo_a * s_h[nxt][lane] + wo_b * s_h[nxt][64 + lane];            \
      p += __shfl_down(p, 32); p += __shfl_down(p, 16); p += __shfl_down(p, 8);\
      p += __shfl_down(p, 4);  p += __shfl_down(p, 2);  p += __shfl_down(p, 1);\
      if (lane == 0) outp[(t) * 2 + kk] = p + bo_r;                            \
    }                                                                          \
  } while (0)

  #pragma unroll 1
  for (int t = 0; t < T_; t += 2){
    STEP(t,     WA, WB);
    STEP(t + 1, WB, WA);
  }
#undef STEP
}

extern "C" void kernel_launch(void* const* d_in, const int* in_sizes, int n_in,
                              void* d_out, int out_size, void* d_ws, size_t ws_size,
                              hipStream_t stream) {
  const float* stim = (const float*)d_in[0];
  const int*   swid = (const int*)  d_in[1];
  const float* mask = (const float*)d_in[2];
  const float* Win  = (const float*)d_in[3];
  const float* binp = (const float*)d_in[4];
  const float* Whr  = (const float*)d_in[5];
  const float* Whz  = (const float*)d_in[6];
  const float* Whn  = (const float*)d_in[7];
  const float* bhr  = (const float*)d_in[8];
  const float* bhz  = (const float*)d_in[9];
  const float* bhn  = (const float*)d_in[10];
  const float* Wo   = (const float*)d_in[11];
  const float* bo   = (const float*)d_in[12];

  uint4* wpk = (uint4*)d_ws;   // 589824 bytes used

  pack_weights<<<144, 256, 0, stream>>>(Whr, Whz, Whn, wpk);
  gru_run<<<B_, 384, 0, stream>>>(stim, swid, mask, Win, binp,
                                  bhr, bhz, bhn, Wo, bo, wpk, (float*)d_out);
}

// Round 6
// 684.441 us; speedup vs baseline: 1.1619x; 1.1619x over previous
//
#include <hip/hip_runtime.h>
#include <stdint.h>

#define B_  256
#define T_  512
#define H_  128
#define NSW 6

typedef __bf16 bf2_t __attribute__((ext_vector_type(2)));

// float -> bf16 round-to-nearest-even
__device__ __forceinline__ unsigned short f2bf(float f){
  unsigned u = __float_as_uint(f);
  unsigned r = u + 0x7FFFu + ((u >> 16) & 1u);
  return (unsigned short)(r >> 16);
}

// acc += dot2(bf16x2 w, bf16x2 h)
__device__ __forceinline__ float dot2bf(unsigned wpair, unsigned hpair, float acc){
#if __has_builtin(__builtin_amdgcn_fdot2_f32_bf16)
  return __builtin_amdgcn_fdot2_f32_bf16(__builtin_bit_cast(bf2_t, wpair),
                                         __builtin_bit_cast(bf2_t, hpair), acc, false);
#else
  asm("v_dot2_f32_bf16 %0, %1, %2, %0" : "+v"(acc) : "v"(wpair), "v"(hpair));
  return acc;
#endif
}

// LDS-only barrier: drains lgkmcnt but NOT vmcnt -> weight prefetch stays in flight.
__device__ __forceinline__ void lds_barrier(){
  asm volatile("s_waitcnt lgkmcnt(0)\ns_barrier" ::: "memory");
}

// Pack weights: dst[(g*6+s)*2048 + j8*128 + i] = uint4 of bf16 W_g[s][i][8*j8+0..7]
__global__ __launch_bounds__(256) void pack_weights(const float* __restrict__ Wr,
                                                    const float* __restrict__ Wz,
                                                    const float* __restrict__ Wn,
                                                    uint4* __restrict__ dst){
  int idx = blockIdx.x * 256 + threadIdx.x;
  if (idx >= 3 * NSW * 2048) return;
  int g  = idx / (NSW * 2048);
  int r0 = idx % (NSW * 2048);
  int s  = r0 / 2048;
  int q  = r0 % 2048;
  int j8 = q / 128;
  int i  = q % 128;
  const float* W = (g == 0) ? Wr : (g == 1) ? Wz : Wn;
  const float* src = W + (size_t)s * (H_*H_) + (size_t)i * H_ + 8 * j8;
  uint4 o;
  o.x = (unsigned)f2bf(src[0]) | ((unsigned)f2bf(src[1]) << 16);
  o.y = (unsigned)f2bf(src[2]) | ((unsigned)f2bf(src[3]) << 16);
  o.z = (unsigned)f2bf(src[4]) | ((unsigned)f2bf(src[5]) << 16);
  o.w = (unsigned)f2bf(src[6]) | ((unsigned)f2bf(src[7]) << 16);
  dst[idx] = o;
}

__global__ __launch_bounds__(384, 1) void gru_run(const float* __restrict__ stim,
    const int*   __restrict__ swid,  const float* __restrict__ mask,
    const float* __restrict__ Win,   const float* __restrict__ binp,
    const float* __restrict__ b_hr,  const float* __restrict__ b_hz, const float* __restrict__ b_hn,
    const float* __restrict__ Wo,    const float* __restrict__ bo,
    const uint4* __restrict__ Wpk,   float* __restrict__ out)
{
  const int b    = blockIdx.x;
  const int tid  = threadIdx.x;
  const int g    = tid >> 7;
  const int i    = tid & 127;
  const int lane = tid & 63;

  __shared__ float    s_stim[T_ * 8];     // 16 KB
  __shared__ float    s_mask[T_];         //  2 KB
  __shared__ int      s_sid[T_];          //  2 KB
  __shared__ float    s_b[3 * NSW * H_];  //  9 KB
  __shared__ float    s_r[H_];
  __shared__ float    s_z[H_];
  __shared__ float    s_h[2][H_];         // fp32 h state
  __shared__ unsigned s_hb[2][64];        // h packed as bf16 pairs

  // ---- preload chain-local data ----
  for (int k = tid; k < T_ * 8; k += 384) s_stim[k] = stim[(size_t)b * T_ * 8 + k];
  for (int k = tid; k < T_; k += 384){
    s_mask[k] = mask[(size_t)b * T_ + k];
    int ss = swid[(size_t)b * T_ + k];
    s_sid[k] = ss < 0 ? 0 : (ss > NSW - 1 ? NSW - 1 : ss);
  }
  for (int k = tid; k < NSW * H_; k += 384){
    s_b[k]                = b_hr[k];
    s_b[NSW * H_ + k]     = b_hz[k];
    s_b[2 * NSW * H_ + k] = b_hn[k];
  }
  if (tid < H_) s_h[0][tid] = 0.f;
  if (tid < 64) s_hb[0][tid] = 0u;

  float winr[8];
  #pragma unroll
  for (int s2 = 0; s2 < 8; ++s2) winr[s2] = Win[tid * 8 + s2];
  const float binr = binp[tid];

  float wo_a = 0.f, wo_b = 0.f, bo_r = 0.f;
  const int kk = (tid >= 192 && tid < 256) ? 1 : 0;
  if (g == 1){
    wo_a = Wo[kk * H_ + lane];
    wo_b = Wo[kk * H_ + 64 + lane];
    bo_r = bo[kk];
  }

  const uint4* gbase = Wpk + (size_t)g * (NSW * 2048) + i;
  float* outp = out + (size_t)b * T_ * 2;

  __syncthreads();

  // sid pipeline carried in SGPRs: sc = sid[t], sn = sid[t+1]
  int sc = __builtin_amdgcn_readfirstlane(s_sid[0]);
  int sn = __builtin_amdgcn_readfirstlane(s_sid[1]);

  // preload step-0 weights (sid = sc)
  uint4 WA[16], WB[16];
  {
    const uint4* wp = gbase + (size_t)sc * 2048;
    #pragma unroll
    for (int j = 0; j < 16; ++j) WA[j] = wp[j * 128];
  }

#define STEP(t, WC, WN) do {                                                   \
    const int cur = (t) & 1, nxt = cur ^ 1;                                    \
    /* issue next-step prefetch immediately: address is ready (sn in SGPR) */  \
    { const uint4* wp = gbase + (size_t)sn * 2048;                             \
      _Pragma("unroll")                                                        \
      for (int j = 0; j < 16; ++j) WN[j] = wp[j * 128]; }                      \
    /* start LDS read of sid[t+2] (consumed at step end) */                    \
    int tn2 = ((t) + 2 < T_) ? (t) + 2 : T_ - 1;                               \
    int snl = s_sid[tn2];                                                      \
    /* fence: loads may not sink below, compute may not hoist above */         \
    __builtin_amdgcn_sched_barrier(0);                                         \
    unsigned hp = s_hb[cur][lane];                                             \
    float4 sa = *reinterpret_cast<const float4*>(&s_stim[(t) * 8]);            \
    float4 sb = *reinterpret_cast<const float4*>(&s_stim[(t) * 8 + 4]);        \
    float x = binr + winr[0]*sa.x + winr[1]*sa.y + winr[2]*sa.z + winr[3]*sa.w \
                   + winr[4]*sb.x + winr[5]*sb.y + winr[6]*sb.z + winr[7]*sb.w;\
    float a0 = 0.f, a1 = 0.f, a2 = 0.f, a3 = 0.f;                              \
    _Pragma("unroll")                                                          \
    for (int j8 = 0; j8 < 16; ++j8){                                           \
      uint4 w = WC[j8];                                                        \
      unsigned h0 = (unsigned)__builtin_amdgcn_readlane((int)hp, 4*j8 + 0);    \
      unsigned h1 = (unsigned)__builtin_amdgcn_readlane((int)hp, 4*j8 + 1);    \
      unsigned h2 = (unsigned)__builtin_amdgcn_readlane((int)hp, 4*j8 + 2);    \
      unsigned h3 = (unsigned)__builtin_amdgcn_readlane((int)hp, 4*j8 + 3);    \
      a0 = dot2bf(w.x, h0, a0);                                                \
      a1 = dot2bf(w.y, h1, a1);                                                \
      a2 = dot2bf(w.z, h2, a2);                                                \
      a3 = dot2bf(w.w, h3, a3);                                                \
    }                                                                          \
    float acc = ((a0 + a1) + (a2 + a3)) + s_b[g * (NSW*H_) + sc * H_ + i];     \
    if (g == 0)      s_r[i] = 1.f / (1.f + __expf(-(x + acc)));                \
    else if (g == 1) s_z[i] = 1.f / (1.f + __expf(-(x + acc)));                \
    lds_barrier();                                                             \
    if (g == 2){                                                               \
      float r = s_r[i], z = s_z[i], hprev = s_h[cur][i];                       \
      float e = __expf(2.f * (x + r * acc));                                   \
      float n = 1.f - 2.f / (e + 1.f);                                         \
      float hnew = (1.f - z) * n + z * hprev;                                  \
      float mt = s_mask[(t)];                                                  \
      float ho = mt * hnew + (1.f - mt) * hprev;                               \
      s_h[nxt][i] = ho;                                                        \
      ((unsigned short*)s_hb[nxt])[i] = f2bf(ho);                              \
    }                                                                          \
    lds_barrier();                                                             \
    if (g == 1){                                                               \
      float p = wo_a * s_h[nxt][lane] + wo_b * s_h[nxt][64 + lane];            \
      p += __shfl_down(p, 32); p += __shfl_down(p, 16); p += __shfl_down(p, 8);\
      p += __shfl_down(p, 4);  p += __shfl_down(p, 2);  p += __shfl_down(p, 1);\
      if (lane == 0) outp[(t) * 2 + kk] = p + bo_r;                            \
    }                                                                          \
    sc = sn;                                                                   \
    sn = __builtin_amdgcn_readfirstlane(snl);                                  \
  } while (0)

  #pragma unroll 1
  for (int t = 0; t < T_; t += 2){
    STEP(t,     WA, WB);
    STEP(t + 1, WB, WA);
  }
#undef STEP
}

extern "C" void kernel_launch(void* const* d_in, const int* in_sizes, int n_in,
                              void* d_out, int out_size, void* d_ws, size_t ws_size,
                              hipStream_t stream) {
  const float* stim = (const float*)d_in[0];
  const int*   swid = (const int*)  d_in[1];
  const float* mask = (const float*)d_in[2];
  const float* Win  = (const float*)d_in[3];
  const float* binp = (const float*)d_in[4];
  const float* Whr  = (const float*)d_in[5];
  const float* Whz  = (const float*)d_in[6];
  const float* Whn  = (const float*)d_in[7];
  const float* bhr  = (const float*)d_in[8];
  const float* bhz  = (const float*)d_in[9];
  const float* bhn  = (const float*)d_in[10];
  const float* Wo   = (const float*)d_in[11];
  const float* bo   = (const float*)d_in[12];

  uint4* wpk = (uint4*)d_ws;   // 589824 bytes used

  pack_weights<<<144, 256, 0, stream>>>(Whr, Whz, Whn, wpk);
  gru_run<<<B_, 384, 0, stream>>>(stim, swid, mask, Win, binp,
                                  bhr, bhz, bhn, Wo, bo, wpk, (float*)d_out);
}